// Round 1
// baseline (251.967 us; speedup 1.0000x reference)
//
#include <hip/hip_runtime.h>
#include <math.h>

#define HH 128
#define WW 128

// One block per batch element. 256 threads × 16 iterations × float4 = 16384 pixels.
// out[b, y, x] = norm_b * exp(P*dx^2 + Q*dx*dy + R*dy^2), dx = x - mux, dy = y - muy.
__global__ __launch_bounds__(256) void MomentsToImage_kernel(
    const float* __restrict__ moments, float* __restrict__ out) {
    const int b = blockIdx.x;
    const float* m = moments + (size_t)b * 6;

    const float sx = (float)(WW - 1);   // 127
    const float sy = (float)(HH - 1);   // 127

    float m0 = m[0], m1 = m[1], m2 = m[2], m3 = m[3], m4 = m[4], m5 = m[5];

    float mux = tanhf(m0) * (sx * 0.5f) + (sx * 0.5f);
    float muy = tanhf(m1) * (sy * 0.5f) + (sy * 0.5f);

    float t0 = fminf(fmaxf(tanhf(m2), 0.03f),   1.0f);
    float t1 = fminf(fmaxf(tanhf(m3), -0.999f), 0.999f);
    float t2 = fminf(fmaxf(tanhf(m4), 0.03f),   1.0f);

    float a  = t0 * (3.0f * sx);
    float bb = t1 * sqrtf(t0 * t2 * (9.0f * sx * sy));
    float c  = t2 * (3.0f * sy);

    float det = a * c - bb * bb;
    float it  = 10.0f / (1.0f + __expf(-m5));          // 10 * sigmoid(m5)
    float norm = it / (6.28318530717958647692f * sqrtf(det));

    float inv_det = 1.0f / det;
    float P = -0.5f * c * inv_det;   // coeff of dx^2
    float Q =  bb * inv_det;         // coeff of dx*dy  (= +b/det, from -0.5 * (-2b))
    float R = -0.5f * a * inv_det;   // coeff of dy^2

    float4* out4 = (float4*)(out + (size_t)b * (HH * WW));

    #pragma unroll
    for (int i = 0; i < 16; ++i) {
        int v = i * 256 + threadIdx.x;   // float4 index within the image
        int p = v << 2;                  // pixel index
        float dy = (float)(p >> 7) - muy;        // y
        float dx = (float)(p & 127) - mux;       // x (4 consecutive share y)

        float rterm = R * dy * dy;
        float qdy   = Q * dy;

        float4 o;
        float d0 = dx;
        o.x = norm * __expf((P * d0 + qdy) * d0 + rterm);
        float d1 = dx + 1.0f;
        o.y = norm * __expf((P * d1 + qdy) * d1 + rterm);
        float d2 = dx + 2.0f;
        o.z = norm * __expf((P * d2 + qdy) * d2 + rterm);
        float d3 = dx + 3.0f;
        o.w = norm * __expf((P * d3 + qdy) * d3 + rterm);
        out4[v] = o;
    }
}

extern "C" void kernel_launch(void* const* d_in, const int* in_sizes, int n_in,
                              void* d_out, int out_size, void* d_ws, size_t ws_size,
                              hipStream_t stream) {
    const float* moments = (const float*)d_in[0];
    float* out = (float*)d_out;
    int B = in_sizes[0] / 6;             // 4096
    MomentsToImage_kernel<<<dim3(B), dim3(256), 0, stream>>>(moments, out);
}